// Round 2
// baseline (27771.881 us; speedup 1.0000x reference)
//
#include <hip/hip_runtime.h>

// B=8, T=1024, E=768, H=12.  fp32 correctness baseline, ws-size adaptive.

#define BK 16

// Generic batched fp32 GEMM with:
//  - optional affine A-window (aShift/aHi) : A element (m,k) = (0 <= m*lda+k+aShift < aHi)
//      ? A[m*lda+k+aShift] : 0   (window bounds are multiples of 4 floats in all uses)
//  - row clip for C writes (mClip), and accumulate mode (C += ...)
// grid: (N/128, Mtiles, batch), block 256, 8x8 accum/thread.
__global__ __launch_bounds__(256, 2)
void gemm128(const float* __restrict__ A, const float* __restrict__ B,
             float* __restrict__ C,
             int K, int lda, int ldb, int ldc,
             long long sA, long long sB, long long sC,
             long long aShift, long long aHi,
             int mClip, int accum)
{
    __shared__ float As[BK][128 + 4];   // As[k][m]
    __shared__ float Bs[BK][128 + 4];   // Bs[k][n]

    const int tid = threadIdx.x;
    A += (long long)blockIdx.z * sA;
    B += (long long)blockIdx.z * sB;
    C += (long long)blockIdx.z * sC;
    const int m0 = blockIdx.y * 128;
    const int n0 = blockIdx.x * 128;
    const int tx = tid & 15;
    const int ty = tid >> 4;

    float acc[8][8];
#pragma unroll
    for (int i = 0; i < 8; ++i)
#pragma unroll
        for (int j = 0; j < 8; ++j) acc[i][j] = 0.f;

    for (int k0 = 0; k0 < K; k0 += BK) {
#pragma unroll
        for (int l = 0; l < 2; ++l) {
            int idx = tid + l * 256;
            // A tile: 128 rows x 16 k
            int ar = idx >> 2, ak = (idx & 3) << 2;
            long long aoff = (long long)(m0 + ar) * lda + (k0 + ak) + aShift;
            float4 av = make_float4(0.f, 0.f, 0.f, 0.f);
            if (aoff >= 0 && aoff < aHi)
                av = *(const float4*)&A[aoff];
            As[ak + 0][ar] = av.x;
            As[ak + 1][ar] = av.y;
            As[ak + 2][ar] = av.z;
            As[ak + 3][ar] = av.w;
            // B tile: 16 k x 128 n
            int br = idx >> 5, bc = (idx & 31) << 2;
            *(float4*)&Bs[br][bc] =
                *(const float4*)&B[(long long)(k0 + br) * ldb + n0 + bc];
        }
        __syncthreads();
#pragma unroll
        for (int k = 0; k < BK; ++k) {
            float a[8], b[8];
            *(float4*)&a[0] = *(const float4*)&As[k][ty * 8];
            *(float4*)&a[4] = *(const float4*)&As[k][ty * 8 + 4];
            *(float4*)&b[0] = *(const float4*)&Bs[k][tx * 8];
            *(float4*)&b[4] = *(const float4*)&Bs[k][tx * 8 + 4];
#pragma unroll
            for (int i = 0; i < 8; ++i)
#pragma unroll
                for (int j = 0; j < 8; ++j)
                    acc[i][j] = fmaf(a[i], b[j], acc[i][j]);
        }
        __syncthreads();
    }

#pragma unroll
    for (int i = 0; i < 8; ++i) {
        int row = m0 + ty * 8 + i;
        if (row < mClip) {
            long long roff = (long long)row * ldc + n0 + tx * 8;
            float4 r0 = *(float4*)&acc[i][0];
            float4 r1 = *(float4*)&acc[i][4];
            if (accum) {
                float4 c0 = *(const float4*)&C[roff];
                float4 c1 = *(const float4*)&C[roff + 4];
                r0.x += c0.x; r0.y += c0.y; r0.z += c0.z; r0.w += c0.w;
                r1.x += c1.x; r1.y += c1.y; r1.z += c1.z; r1.w += c1.w;
            }
            *(float4*)&C[roff]     = r0;
            *(float4*)&C[roff + 4] = r1;
        }
    }
}

// Column softmax (normalize over QUERY axis = rows), scale applied pre-max.
// grid: (T/64, nb); block 256 = 64 cols x 4 row-segments.
__global__ __launch_bounds__(256)
void col_softmax(float* __restrict__ S, int T, float scale)
{
    const int tid = threadIdx.x;
    const int jl = tid & 63;
    const int seg = tid >> 6;
    const int j = blockIdx.x * 64 + jl;
    float* Sb = S + (long long)blockIdx.y * T * T;
    const int rps = T >> 2;
    const int r0 = seg * rps;

    float m = -3.4e38f, s = 0.f;
    for (int r = 0; r < rps; ++r) {
        float v = Sb[(long long)(r0 + r) * T + j] * scale;
        float mn = fmaxf(m, v);
        s = s * __expf(m - mn) + __expf(v - mn);
        m = mn;
    }
    __shared__ float sm[4][64], ss[4][64];
    sm[seg][jl] = m;
    ss[seg][jl] = s;
    __syncthreads();
    float mt = -3.4e38f, st = 0.f;
#pragma unroll
    for (int q = 0; q < 4; ++q) {
        float mq = sm[q][jl], sq = ss[q][jl];
        float mn = fmaxf(mt, mq);
        st = st * __expf(mt - mn) + sq * __expf(mq - mn);
        mt = mn;
    }
    const float inv = 1.f / st;
    for (int r = 0; r < rps; ++r) {
        long long off = (long long)(r0 + r) * T + j;
        Sb[off] = __expf(Sb[off] * scale - mt) * inv;
    }
}

extern "C" void kernel_launch(void* const* d_in, const int* in_sizes, int n_in,
                              void* d_out, int out_size, void* d_ws, size_t ws_size,
                              hipStream_t stream)
{
    const float* x  = (const float*)d_in[0];   // (B,T,E)
    const float* WQ = (const float*)d_in[1];   // (H,E,E)
    const float* WK = (const float*)d_in[2];
    const float* WV = (const float*)d_in[3];
    const float* WO = (const float*)d_in[4];   // (H*E, E)
    float* out = (float*)d_out;                // (B,T,E)

    const int B = 8, T = 1024, E = 768, H = 12;
    const long long TE = (long long)T * E;        // 786432
    const long long TT = (long long)T * T;        // 1048576
    const long long BTE = (long long)B * TE;
    const long long HE = (long long)H * E;        // 9216

    // Plan C: per-head, all batches.  ws = 4*B*T*E + B*T*T floats = 128 MiB.
    // Plan D: per-(head,batch).       ws = 4*T*E + T*T floats   = 16 MiB.
    const size_t needC = (size_t)(4 * BTE + B * TT) * sizeof(float);
    const bool planC = ws_size >= needC;
    const int nb = planC ? B : 1;               // batches per launch
    const long long qTE = planC ? TE : 0;       // batch strides inside launch
    const long long qTT = planC ? TT : 0;

    float* Qh = (float*)d_ws;
    float* Kh = Qh + (size_t)nb * TE;
    float* Vh = Kh + (size_t)nb * TE;
    float* Zh = Vh + (size_t)nb * TE;
    float* Sh = Zh + (size_t)nb * TE;

    // Final projection accumulates per head -> zero-init output.
    hipMemsetAsync(out, 0, (size_t)B * TE * sizeof(float), stream);

    dim3 blk(256);
    const int nOuter = planC ? 1 : B;           // host batch loop count

    for (int h = 0; h < H; ++h) {
        // i-window of the quirky reshape covered by this head:
        // out row i reads Zc flat [i*9216, (i+1)*9216); head h owns flat
        // [h*786432, (h+1)*786432).  Both bounds are multiples of 768.
        const int i_lo = (int)(((long long)h * TE) / HE);
        const long long aShift = (long long)i_lo * HE - (long long)h * TE;

        for (int bb = 0; bb < nOuter; ++bb) {
            const float* xb = x + (planC ? 0 : (long long)bb * TE);
            float* outb = out + (planC ? 0 : (long long)bb * TE);
            const int Mproj = planC ? B * T : T;

            // Q/K/V projections: (Mproj x E) @ (E x E)
            dim3 gp(E / 128, Mproj / 128, 1);
            gemm128<<<gp, blk, 0, stream>>>(xb, WQ + (size_t)h * E * E, Qh,
                E, E, E, E, 0, 0, 0, 0, (long long)Mproj * E, Mproj, 0);
            gemm128<<<gp, blk, 0, stream>>>(xb, WK + (size_t)h * E * E, Kh,
                E, E, E, E, 0, 0, 0, 0, (long long)Mproj * E, Mproj, 0);
            gemm128<<<gp, blk, 0, stream>>>(xb, WV + (size_t)h * E * E, Vh,
                E, E, E, E, 0, 0, 0, 0, (long long)Mproj * E, Mproj, 0);

            // Scores: Q_b (T x E) @ K_b flat reinterpreted as (E x T), ldb=T.
            dim3 gs(T / 128, T / 128, nb);
            gemm128<<<gs, blk, 0, stream>>>(Qh, Kh, Sh,
                E, E, T, T, qTE, qTE, qTT, 0, TE, T, 0);

            // Softmax over query axis with 1/sqrt(T) pre-scale.
            col_softmax<<<dim3(T / 64, nb), blk, 0, stream>>>(Sh, T, 0.03125f);

            // Z_h = A (T x T) @ V_b (T x E)
            dim3 gz(E / 128, T / 128, nb);
            gemm128<<<gz, blk, 0, stream>>>(Sh, Vh, Zh,
                T, T, E, E, qTT, qTE, qTE, 0, TT, T, 0);

            // Fused final projection contribution of head h:
            // out_b[i_lo .. , :] += A_h @ WO,  A_h[i,j] = Zh_flat[i*9216+j+aShift]
            // (zero outside [0, T*E) window; ~87 live rows -> one 128-row tile)
            dim3 gf(E / 128, 1, nb);
            gemm128<<<gf, blk, 0, stream>>>(Zh, WO, outb + (long long)i_lo * E,
                (int)HE, (int)HE, E, E, qTE, 0, qTE,
                aShift, TE, T - i_lo, 1);
        }
    }
}

// Round 3
// 19447.697 us; speedup vs baseline: 1.4280x; 1.4280x over previous
//
#include <hip/hip_runtime.h>

// B=8, T=1024, E=768, H=12.
// Split-bf16 MFMA GEMM: fp32 operands are split into (hi, lo) bf16 on the fly;
// D = Ah*Bh + Al*Bh + Ah*Bl accumulated in fp32 -> ~1e-5 relative accuracy.

typedef __bf16 bf16x8 __attribute__((ext_vector_type(8)));
typedef __bf16 bf16x4 __attribute__((ext_vector_type(4)));
typedef float  f32x4  __attribute__((ext_vector_type(4)));

#define BK 32
#define APITCH 40    // bf16 per LDS A row (32+8: keeps 16B align, spreads banks)
#define BPITCH 130   // fp32 per LDS B row (128+2: quads hit disjoint bank sets)

// C[z] = A[z] (Mx K, lda) @ B[z] (K x N, ldb), 128x128 tile per block.
// A supports affine window: element (m,k) = (0 <= m*lda+k+aShift < aHi) ? ... : 0.
// mClip clips C-row writes; accum makes it C += .
__global__ __launch_bounds__(256, 2)
void gemm_sp(const float* __restrict__ A, const float* __restrict__ B,
             float* __restrict__ C,
             int K, int lda, int ldb, int ldc,
             long long sA, long long sB, long long sC,
             long long aShift, long long aHi,
             int mClip, int accum)
{
    __shared__ __bf16 Ah[128][APITCH];
    __shared__ __bf16 Al[128][APITCH];
    __shared__ float  Bf[BK][BPITCH];

    const int tid = threadIdx.x;
    A += (long long)blockIdx.z * sA;
    B += (long long)blockIdx.z * sB;
    C += (long long)blockIdx.z * sC;
    const int m0 = blockIdx.y * 128;
    const int n0 = blockIdx.x * 128;

    const int lane = tid & 63;
    const int wave = tid >> 6;
    const int wm = (wave & 1) << 6;    // wave's 64x64 quadrant
    const int wn = (wave >> 1) << 6;
    const int lr = lane & 15;
    const int lq = lane >> 4;

    f32x4 acc[4][4] = {};

    for (int k0 = 0; k0 < K; k0 += BK) {
        // ---- stage A: 128x32 fp32 -> split bf16 hi/lo in LDS ----
#pragma unroll
        for (int l = 0; l < 4; ++l) {
            int idx = tid + (l << 8);
            int ar = idx >> 3;
            int ak = (idx & 7) << 2;
            long long aoff = (long long)(m0 + ar) * lda + (k0 + ak) + aShift;
            float4 v = make_float4(0.f, 0.f, 0.f, 0.f);
            if (aoff >= 0 && aoff < aHi) v = *(const float4*)&A[aoff];
            bf16x4 h, lo;
            h[0] = (__bf16)v.x; h[1] = (__bf16)v.y;
            h[2] = (__bf16)v.z; h[3] = (__bf16)v.w;
            lo[0] = (__bf16)(v.x - (float)h[0]);
            lo[1] = (__bf16)(v.y - (float)h[1]);
            lo[2] = (__bf16)(v.z - (float)h[2]);
            lo[3] = (__bf16)(v.w - (float)h[3]);
            *(bf16x4*)&Ah[ar][ak] = h;
            *(bf16x4*)&Al[ar][ak] = lo;
        }
        // ---- stage B: 32x128 fp32 direct (split happens at frag read) ----
#pragma unroll
        for (int l = 0; l < 4; ++l) {
            int idx = tid + (l << 8);
            int bk = idx >> 5;
            int bn = (idx & 31) << 2;
            float4 v = *(const float4*)&B[(long long)(k0 + bk) * ldb + n0 + bn];
            *(float2*)&Bf[bk][bn]     = make_float2(v.x, v.y);
            *(float2*)&Bf[bk][bn + 2] = make_float2(v.z, v.w);
        }
        __syncthreads();

        bf16x8 fAh[4], fAl[4];
#pragma unroll
        for (int mi = 0; mi < 4; ++mi) {
            fAh[mi] = *(const bf16x8*)&Ah[wm + (mi << 4) + lr][lq << 3];
            fAl[mi] = *(const bf16x8*)&Al[wm + (mi << 4) + lr][lq << 3];
        }
#pragma unroll
        for (int ni = 0; ni < 4; ++ni) {
            const int n = wn + (ni << 4) + lr;
            bf16x8 bh, bl;
#pragma unroll
            for (int j = 0; j < 8; ++j) {
                float v = Bf[(lq << 3) + j][n];
                __bf16 h = (__bf16)v;
                bh[j] = h;
                bl[j] = (__bf16)(v - (float)h);
            }
#pragma unroll
            for (int mi = 0; mi < 4; ++mi) {
                acc[mi][ni] = __builtin_amdgcn_mfma_f32_16x16x32_bf16(fAh[mi], bh, acc[mi][ni], 0, 0, 0);
                acc[mi][ni] = __builtin_amdgcn_mfma_f32_16x16x32_bf16(fAl[mi], bh, acc[mi][ni], 0, 0, 0);
                acc[mi][ni] = __builtin_amdgcn_mfma_f32_16x16x32_bf16(fAh[mi], bl, acc[mi][ni], 0, 0, 0);
            }
        }
        __syncthreads();
    }

    // Epilogue: C/D layout col = lane&15, row = (lane>>4)*4 + reg  [m89]
#pragma unroll
    for (int mi = 0; mi < 4; ++mi)
#pragma unroll
        for (int r = 0; r < 4; ++r) {
            int row = m0 + wm + (mi << 4) + (lq << 2) + r;
            if (row < mClip) {
#pragma unroll
                for (int ni = 0; ni < 4; ++ni) {
                    long long off = (long long)row * ldc + n0 + wn + (ni << 4) + lr;
                    float v = acc[mi][ni][r];
                    if (accum) v += C[off];
                    C[off] = v;
                }
            }
        }
}

// Column softmax (normalize over QUERY axis = rows), scale applied pre-max.
// grid: (T/64, nb); block 256 = 64 cols x 4 row-segments. In-place fp32.
__global__ __launch_bounds__(256)
void col_softmax(float* __restrict__ S, int T, float scale)
{
    const int tid = threadIdx.x;
    const int jl = tid & 63;
    const int seg = tid >> 6;
    const int j = blockIdx.x * 64 + jl;
    float* Sb = S + (long long)blockIdx.y * T * T;
    const int rps = T >> 2;
    const int r0 = seg * rps;

    float m = -3.4e38f, s = 0.f;
    for (int r = 0; r < rps; ++r) {
        float v = Sb[(long long)(r0 + r) * T + j] * scale;
        float mn = fmaxf(m, v);
        s = s * __expf(m - mn) + __expf(v - mn);
        m = mn;
    }
    __shared__ float sm[4][64], ss[4][64];
    sm[seg][jl] = m;
    ss[seg][jl] = s;
    __syncthreads();
    float mt = -3.4e38f, st = 0.f;
#pragma unroll
    for (int q = 0; q < 4; ++q) {
        float mq = sm[q][jl], sq = ss[q][jl];
        float mn = fmaxf(mt, mq);
        st = st * __expf(mt - mn) + sq * __expf(mq - mn);
        mt = mn;
    }
    const float inv = 1.f / st;
    for (int r = 0; r < rps; ++r) {
        long long off = (long long)(r0 + r) * T + j;
        Sb[off] = __expf(Sb[off] * scale - mt) * inv;
    }
}

extern "C" void kernel_launch(void* const* d_in, const int* in_sizes, int n_in,
                              void* d_out, int out_size, void* d_ws, size_t ws_size,
                              hipStream_t stream)
{
    const float* x  = (const float*)d_in[0];   // (B,T,E)
    const float* WQ = (const float*)d_in[1];   // (H,E,E)
    const float* WK = (const float*)d_in[2];
    const float* WV = (const float*)d_in[3];
    const float* WO = (const float*)d_in[4];   // (H*E, E)
    float* out = (float*)d_out;                // (B,T,E)

    const int B = 8, T = 1024, E = 768, H = 12;
    const long long TE = (long long)T * E;     // 786432
    const long long TT = (long long)T * T;     // 1048576
    const long long HE = (long long)H * E;     // 9216
    const long long BIG = 1LL << 62;
    const int NOCLIP = 1 << 30;

    // Dynamic chunking: one slice = Q,K,V,Z (TE each) + S (TT) fp32 = 16 MiB.
    const long long sliceF = 4 * TE + TT;      // 4,194,304 floats
    long long wsF = (long long)(ws_size / 4);
    int NC = (int)(wsF / sliceF);
    if (NC < 1) NC = 1;
    if (NC > B) NC = B;

    float* Qh = (float*)d_ws;
    float* Kh = Qh + (size_t)NC * TE;
    float* Vh = Kh + (size_t)NC * TE;
    float* Zh = Vh + (size_t)NC * TE;
    float* Sh = Zh + (size_t)NC * TE;

    hipMemsetAsync(out, 0, (size_t)B * TE * sizeof(float), stream);

    dim3 blk(256);

    for (int h = 0; h < H; ++h) {
        // Quirky-reshape window: out row i reads Zc flat [i*9216,(i+1)*9216);
        // head h owns flat [h*786432,(h+1)*786432). Bounds multiples of 768.
        const int i_lo = (int)(((long long)h * TE) / HE);
        const long long aShift = (long long)i_lo * HE - (long long)h * TE;

        for (int b0 = 0; b0 < B; b0 += NC) {
            const int nb = (B - b0 < NC) ? (B - b0) : NC;

            // Q/K/V projections: (nb*T x E) @ (E x E), contiguous batches.
            dim3 gp(E / 128, nb * T / 128, 1);
            gemm_sp<<<gp, blk, 0, stream>>>(x + (long long)b0 * TE,
                WQ + (size_t)h * E * E, Qh, E, E, E, E, 0, 0, 0,
                0, BIG, NOCLIP, 0);
            gemm_sp<<<gp, blk, 0, stream>>>(x + (long long)b0 * TE,
                WK + (size_t)h * E * E, Kh, E, E, E, E, 0, 0, 0,
                0, BIG, NOCLIP, 0);
            gemm_sp<<<gp, blk, 0, stream>>>(x + (long long)b0 * TE,
                WV + (size_t)h * E * E, Vh, E, E, E, E, 0, 0, 0,
                0, BIG, NOCLIP, 0);

            // Scores: Q_b (T x E) @ K_b flat reinterpreted as (E x T), ldb=T.
            dim3 gs(T / 128, T / 128, nb);
            gemm_sp<<<gs, blk, 0, stream>>>(Qh, Kh, Sh, E, E, T, T,
                TE, TE, TT, 0, BIG, NOCLIP, 0);

            // Softmax over query axis with 1/sqrt(T) pre-scale (in place).
            col_softmax<<<dim3(T / 64, nb), blk, 0, stream>>>(Sh, T, 0.03125f);

            // Z = A (T x T) @ V_b (T x E)
            dim3 gz(E / 128, T / 128, nb);
            gemm_sp<<<gz, blk, 0, stream>>>(Sh, Vh, Zh, T, T, E, E,
                TT, TE, TE, 0, BIG, NOCLIP, 0);

            // Final projection contribution of head h (accumulate):
            // out_b[i_lo+m,:] += A_h @ WO, A_h[m,k] = Zflat[m*9216+k+aShift]
            dim3 gf(E / 128, 1, nb);
            gemm_sp<<<gf, blk, 0, stream>>>(Zh, WO,
                out + (long long)b0 * TE + (long long)i_lo * E,
                (int)HE, (int)HE, E, E, TE, 0, TE,
                aShift, TE, T - i_lo, 1);
        }
    }
}

// Round 4
// 11861.559 us; speedup vs baseline: 2.3413x; 1.6396x over previous
//
#include <hip/hip_runtime.h>

// B=8, T=1024, E=768, H=12.
// Split-bf16 MFMA GEMM: fp32 operands split into (hi, lo) bf16 AT LDS STAGING;
// D = Ah*Bh + Al*Bh + Ah*Bl accumulated in fp32 -> ~1e-5 relative accuracy.
// Both A and B fragments are contiguous ds_read_b128 (B stored transposed).

typedef __bf16 bf16x8 __attribute__((ext_vector_type(8)));
typedef __bf16 bf16x4 __attribute__((ext_vector_type(4)));
typedef float  f32x4  __attribute__((ext_vector_type(4)));

#define PITCH 40   // bf16 per LDS row (32+8): 16B-aligned frag reads, spread banks

__device__ __forceinline__ void gemm_core(
    const float* __restrict__ A, const float* __restrict__ B, float* __restrict__ C,
    int K, int lda, int ldb, int ldc,
    long long aShift, long long aHi, int mClip, int mode,
    int mtile, int kChunk, int kChunks, int n0)
{
    __shared__ __bf16 Ahi[128][PITCH];
    __shared__ __bf16 Alo[128][PITCH];
    __shared__ __bf16 Bhi[128][PITCH];   // transposed: Bhi[n][k]
    __shared__ __bf16 Blo[128][PITCH];

    const int tid = threadIdx.x;
    const int m0 = mtile * 128;
    const int lane = tid & 63;
    const int wave = tid >> 6;
    const int wm = (wave & 1) << 6;      // wave's 64x64 quadrant
    const int wn = (wave >> 1) << 6;
    const int lr = lane & 15;
    const int lq = lane >> 4;

    f32x4 acc[4][4] = {};

    const int kLen = K / kChunks;
    const int kBeg = kChunk * kLen;

    for (int k0 = kBeg; k0 < kBeg + kLen; k0 += 32) {
        // ---- stage A: 128m x 32k fp32 -> split hi/lo bf16, row-major ----
#pragma unroll
        for (int l = 0; l < 4; ++l) {
            int idx = tid + (l << 8);
            int ar = idx >> 3, ak = (idx & 7) << 2;
            long long aoff = (long long)(m0 + ar) * lda + (k0 + ak) + aShift;
            float4 v = make_float4(0.f, 0.f, 0.f, 0.f);
            if (aoff >= 0 && aoff < aHi) v = *(const float4*)&A[aoff];
            bf16x4 h, lo;
            h[0] = (__bf16)v.x; h[1] = (__bf16)v.y;
            h[2] = (__bf16)v.z; h[3] = (__bf16)v.w;
            lo[0] = (__bf16)(v.x - (float)h[0]);
            lo[1] = (__bf16)(v.y - (float)h[1]);
            lo[2] = (__bf16)(v.z - (float)h[2]);
            lo[3] = (__bf16)(v.w - (float)h[3]);
            *(bf16x4*)&Ahi[ar][ak] = h;
            *(bf16x4*)&Alo[ar][ak] = lo;
        }
        // ---- stage B: 32k x 128n fp32 -> split hi/lo bf16, TRANSPOSED ----
#pragma unroll
        for (int l = 0; l < 4; ++l) {
            int idx = tid + (l << 8);
            int bk = idx >> 5, bn = (idx & 31) << 2;
            float4 v = *(const float4*)&B[(long long)(k0 + bk) * ldb + n0 + bn];
            __bf16 h0 = (__bf16)v.x, h1 = (__bf16)v.y,
                   h2 = (__bf16)v.z, h3 = (__bf16)v.w;
            Bhi[bn + 0][bk] = h0;  Blo[bn + 0][bk] = (__bf16)(v.x - (float)h0);
            Bhi[bn + 1][bk] = h1;  Blo[bn + 1][bk] = (__bf16)(v.y - (float)h1);
            Bhi[bn + 2][bk] = h2;  Blo[bn + 2][bk] = (__bf16)(v.z - (float)h2);
            Bhi[bn + 3][bk] = h3;  Blo[bn + 3][bk] = (__bf16)(v.w - (float)h3);
        }
        __syncthreads();

        bf16x8 ah[4], al[4];
#pragma unroll
        for (int mi = 0; mi < 4; ++mi) {
            ah[mi] = *(const bf16x8*)&Ahi[wm + (mi << 4) + lr][lq << 3];
            al[mi] = *(const bf16x8*)&Alo[wm + (mi << 4) + lr][lq << 3];
        }
#pragma unroll
        for (int ni = 0; ni < 4; ++ni) {
            bf16x8 bh = *(const bf16x8*)&Bhi[wn + (ni << 4) + lr][lq << 3];
            bf16x8 bl = *(const bf16x8*)&Blo[wn + (ni << 4) + lr][lq << 3];
#pragma unroll
            for (int mi = 0; mi < 4; ++mi) {
                acc[mi][ni] = __builtin_amdgcn_mfma_f32_16x16x32_bf16(ah[mi], bh, acc[mi][ni], 0, 0, 0);
                acc[mi][ni] = __builtin_amdgcn_mfma_f32_16x16x32_bf16(al[mi], bh, acc[mi][ni], 0, 0, 0);
                acc[mi][ni] = __builtin_amdgcn_mfma_f32_16x16x32_bf16(ah[mi], bl, acc[mi][ni], 0, 0, 0);
            }
        }
        __syncthreads();
    }

    // Epilogue: C/D layout col = lane&15, row = (lane>>4)*4 + reg  [m89]
#pragma unroll
    for (int mi = 0; mi < 4; ++mi)
#pragma unroll
        for (int r = 0; r < 4; ++r) {
            int row = m0 + wm + (mi << 4) + (lq << 2) + r;
            if (row < mClip) {
#pragma unroll
                for (int ni = 0; ni < 4; ++ni) {
                    long long off = (long long)row * ldc + n0 + wn + (ni << 4) + lr;
                    float v = acc[mi][ni][r];
                    if (mode == 2)      atomicAdd(&C[off], v);
                    else                C[off] = v;
                }
            }
        }
}

// Generic batched GEMM. grid: (N/128, mTiles*kChunks, batch).
__global__ __launch_bounds__(256, 2)
void gemm_one(const float* __restrict__ A, const float* __restrict__ B,
              float* __restrict__ C,
              int K, int lda, int ldb, int ldc,
              long long sA, long long sB, long long sC,
              long long aShift, long long aHi, int mClip, int mode, int kChunks)
{
    A += (long long)blockIdx.z * sA;
    B += (long long)blockIdx.z * sB;
    C += (long long)blockIdx.z * sC;
    int mtile = blockIdx.y / kChunks;
    int kc    = blockIdx.y % kChunks;
    gemm_core(A, B, C, K, lda, ldb, ldc, aShift, aHi, mClip, mode,
              mtile, kc, kChunks, blockIdx.x * 128);
}

// Fused QKV projection: grid (N/128, mTiles, 3); z selects W / output.
__global__ __launch_bounds__(256, 2)
void gemm_qkv(const float* __restrict__ A,
              const float* __restrict__ B0, const float* __restrict__ B1,
              const float* __restrict__ B2,
              float* __restrict__ C0, float* __restrict__ C1, float* __restrict__ C2,
              int K, int lda, int ldb, int ldc)
{
    const float* Bs = (blockIdx.z == 0) ? B0 : (blockIdx.z == 1) ? B1 : B2;
    float*       Cs = (blockIdx.z == 0) ? C0 : (blockIdx.z == 1) ? C1 : C2;
    gemm_core(A, Bs, Cs, K, lda, ldb, ldc, 0, 1LL << 62, 1 << 30, 0,
              blockIdx.y, 0, 1, blockIdx.x * 128);
}

// Column softmax (normalize over QUERY axis = rows), scale applied pre-max.
// grid: (T/64, nb); block 256 = 64 cols x 4 row-segments. In-place fp32.
__global__ __launch_bounds__(256)
void col_softmax(float* __restrict__ S, int T, float scale)
{
    const int tid = threadIdx.x;
    const int jl = tid & 63;
    const int seg = tid >> 6;
    const int j = blockIdx.x * 64 + jl;
    float* Sb = S + (long long)blockIdx.y * T * T;
    const int rps = T >> 2;
    const int r0 = seg * rps;

    float m = -3.4e38f, s = 0.f;
    for (int r = 0; r < rps; ++r) {
        float v = Sb[(long long)(r0 + r) * T + j] * scale;
        float mn = fmaxf(m, v);
        s = s * __expf(m - mn) + __expf(v - mn);
        m = mn;
    }
    __shared__ float sm[4][64], ss[4][64];
    sm[seg][jl] = m;
    ss[seg][jl] = s;
    __syncthreads();
    float mt = -3.4e38f, st = 0.f;
#pragma unroll
    for (int q = 0; q < 4; ++q) {
        float mq = sm[q][jl], sq = ss[q][jl];
        float mn = fmaxf(mt, mq);
        st = st * __expf(mt - mn) + sq * __expf(mq - mn);
        mt = mn;
    }
    const float inv = 1.f / st;
    for (int r = 0; r < rps; ++r) {
        long long off = (long long)(r0 + r) * T + j;
        Sb[off] = __expf(Sb[off] * scale - mt) * inv;
    }
}

extern "C" void kernel_launch(void* const* d_in, const int* in_sizes, int n_in,
                              void* d_out, int out_size, void* d_ws, size_t ws_size,
                              hipStream_t stream)
{
    const float* x  = (const float*)d_in[0];   // (B,T,E)
    const float* WQ = (const float*)d_in[1];   // (H,E,E)
    const float* WK = (const float*)d_in[2];
    const float* WV = (const float*)d_in[3];
    const float* WO = (const float*)d_in[4];   // (H*E, E)
    float* out = (float*)d_out;                // (B,T,E)

    const int B = 8, T = 1024, E = 768, H = 12;
    const long long TE = (long long)T * E;     // 786432
    const long long TT = (long long)T * T;     // 1048576
    const long long HE = (long long)H * E;     // 9216
    const long long BIG = 1LL << 62;
    const int NOCLIP = 1 << 30;

    // Chunking: one slice = Q,K,V,Z (TE each) + S (TT) fp32 = 16 MiB.
    // Profile evidence (round 3): NC=8 path ran -> ws_size >= 128 MiB.
    const long long sliceF = 4 * TE + TT;
    long long wsF = (long long)(ws_size / 4);
    int NC = (int)(wsF / sliceF);
    if (NC < 1) NC = 1;
    if (NC > B) NC = B;

    float* Qh = (float*)d_ws;
    float* Kh = Qh + (size_t)NC * TE;
    float* Vh = Kh + (size_t)NC * TE;
    float* Zh = Vh + (size_t)NC * TE;
    float* Sh = Zh + (size_t)NC * TE;

    hipMemsetAsync(out, 0, (size_t)B * TE * sizeof(float), stream);

    dim3 blk(256);

    for (int h = 0; h < H; ++h) {
        // Quirky-reshape window: out row i reads Zc flat [i*9216,(i+1)*9216);
        // head h owns flat [h*786432,(h+1)*786432). Bounds multiples of 768.
        const int i_lo = (int)(((long long)h * TE) / HE);
        const long long aShift = (long long)i_lo * HE - (long long)h * TE;

        for (int b0 = 0; b0 < B; b0 += NC) {
            const int nb = (B - b0 < NC) ? (B - b0) : NC;

            // Fused Q/K/V projections: (nb*T x E) @ (E x E), z selects W.
            dim3 gp(E / 128, nb * T / 128, 3);
            gemm_qkv<<<gp, blk, 0, stream>>>(x + (long long)b0 * TE,
                WQ + (size_t)h * E * E, WK + (size_t)h * E * E,
                WV + (size_t)h * E * E, Qh, Kh, Vh, E, E, E, E);

            // Scores: Q_b (T x E) @ K_b flat reinterpreted as (E x T), ldb=T.
            dim3 gs(T / 128, T / 128, nb);
            gemm_one<<<gs, blk, 0, stream>>>(Qh, Kh, Sh, E, E, T, T,
                TE, TE, TT, 0, BIG, NOCLIP, 0, 1);

            // Softmax over query axis with 1/sqrt(T) pre-scale (in place).
            col_softmax<<<dim3(T / 64, nb), blk, 0, stream>>>(Sh, T, 0.03125f);

            // Z = A (T x T) @ V_b (T x E)
            dim3 gz(E / 128, T / 128, nb);
            gemm_one<<<gz, blk, 0, stream>>>(Sh, Vh, Zh, T, T, E, E,
                TT, TE, TE, 0, BIG, NOCLIP, 0, 1);

            // Final projection contribution of head h, K-SPLIT x6 + atomics:
            // out_b[i_lo+m,:] += A_h @ WO, A_h[m,k] = Zflat[m*9216+k+aShift]
            dim3 gf(E / 128, 6, nb);   // y = k-chunks (single m-tile)
            gemm_one<<<gf, blk, 0, stream>>>(Zh, WO,
                out + (long long)b0 * TE + (long long)i_lo * E,
                (int)HE, (int)HE, E, E, TE, 0, TE,
                aShift, TE, T - i_lo, 2, 6);
        }
    }
}

// Round 5
// 5332.869 us; speedup vs baseline: 5.2077x; 2.2242x over previous
//
#include <hip/hip_runtime.h>

// B=8, T=1024, E=768, H=12.
// Split-bf16 MFMA GEMM: fp32 operands split into (hi, lo) bf16 at LDS staging;
// D = Ah*Bh + Al*Bh + Ah*Bl accumulated in fp32 -> ~1e-5 relative accuracy.
// Round 5: conflict-free vectorized B staging (k-strided coalesced loads,
// ds_write_b128 into [n][k] layout) + register prefetch software pipeline.

typedef __bf16 bf16x8 __attribute__((ext_vector_type(8)));
typedef __bf16 bf16x4 __attribute__((ext_vector_type(4)));
typedef float  f32x4  __attribute__((ext_vector_type(4)));

#define PITCH 40   // bf16 per LDS row (32+8): 16B-aligned frag reads, spread banks

__device__ __forceinline__ void gemm_core(
    const float* __restrict__ A, const float* __restrict__ B, float* __restrict__ C,
    int K, int lda, int ldb, int ldc,
    long long aShift, long long aHi, int mClip, int mode,
    int mtile, int kChunk, int kChunks, int n0)
{
    __shared__ __bf16 Ahi[128][PITCH];
    __shared__ __bf16 Alo[128][PITCH];
    __shared__ __bf16 Bhi[128][PITCH];   // transposed: Bhi[n][k]
    __shared__ __bf16 Blo[128][PITCH];

    const int tid = threadIdx.x;
    const int m0 = mtile * 128;
    const int lane = tid & 63;
    const int wave = tid >> 6;
    const int wm = (wave & 1) << 6;      // wave's 64x64 quadrant
    const int wn = (wave >> 1) << 6;
    const int lr = lane & 15;
    const int lq = lane >> 4;

    // staging coords
    const int ar0 = tid >> 3;            // A row 0..31 (+32*l)
    const int ak  = (tid & 7) << 2;      // A k-offset 0,4,..,28
    const int nB  = tid & 127;           // B column (one per thread)
    const int kh  = (tid >> 7) << 4;     // B k-half: 0 or 16

    f32x4 acc[4][4] = {};

    const int kLen = K / kChunks;
    const int kBeg = kChunk * kLen;
    const int kEnd = kBeg + kLen;

    float4 rA[4];
    float  rB[16];

    auto loadAB = [&](int k0) {
#pragma unroll
        for (int l = 0; l < 4; ++l) {
            long long aoff = (long long)(m0 + ar0 + l * 32) * lda + (k0 + ak) + aShift;
            float4 v = make_float4(0.f, 0.f, 0.f, 0.f);
            if (aoff >= 0 && aoff < aHi) v = *(const float4*)&A[aoff];
            rA[l] = v;
        }
#pragma unroll
        for (int j = 0; j < 16; ++j)     // lane-coalesced (consecutive nB)
            rB[j] = B[(long long)(k0 + kh + j) * ldb + n0 + nB];
    };

    loadAB(kBeg);

    for (int k0 = kBeg; k0 < kEnd; k0 += 32) {
        // ---- stage A: hi/lo split, row-major, ds_write_b64 ----
#pragma unroll
        for (int l = 0; l < 4; ++l) {
            float4 v = rA[l];
            bf16x4 h, lo;
            h[0] = (__bf16)v.x; h[1] = (__bf16)v.y;
            h[2] = (__bf16)v.z; h[3] = (__bf16)v.w;
            lo[0] = (__bf16)(v.x - (float)h[0]);
            lo[1] = (__bf16)(v.y - (float)h[1]);
            lo[2] = (__bf16)(v.z - (float)h[2]);
            lo[3] = (__bf16)(v.w - (float)h[3]);
            *(bf16x4*)&Ahi[ar0 + l * 32][ak] = h;
            *(bf16x4*)&Alo[ar0 + l * 32][ak] = lo;
        }
        // ---- stage B: hi/lo split, [n][k] layout, ds_write_b128 ----
        {
            bf16x8 bh0, bh1, bl0, bl1;
#pragma unroll
            for (int j = 0; j < 8; ++j) {
                float v0 = rB[j], v1 = rB[j + 8];
                __bf16 h0 = (__bf16)v0, h1 = (__bf16)v1;
                bh0[j] = h0; bl0[j] = (__bf16)(v0 - (float)h0);
                bh1[j] = h1; bl1[j] = (__bf16)(v1 - (float)h1);
            }
            *(bf16x8*)&Bhi[nB][kh]     = bh0;
            *(bf16x8*)&Bhi[nB][kh + 8] = bh1;
            *(bf16x8*)&Blo[nB][kh]     = bl0;
            *(bf16x8*)&Blo[nB][kh + 8] = bl1;
        }
        __syncthreads();

        // prefetch next k-tile while this tile computes
        if (k0 + 32 < kEnd) loadAB(k0 + 32);

        bf16x8 ah[4], al[4];
#pragma unroll
        for (int mi = 0; mi < 4; ++mi) {
            ah[mi] = *(const bf16x8*)&Ahi[wm + (mi << 4) + lr][lq << 3];
            al[mi] = *(const bf16x8*)&Alo[wm + (mi << 4) + lr][lq << 3];
        }
#pragma unroll
        for (int ni = 0; ni < 4; ++ni) {
            bf16x8 bh = *(const bf16x8*)&Bhi[wn + (ni << 4) + lr][lq << 3];
            bf16x8 bl = *(const bf16x8*)&Blo[wn + (ni << 4) + lr][lq << 3];
#pragma unroll
            for (int mi = 0; mi < 4; ++mi) {
                acc[mi][ni] = __builtin_amdgcn_mfma_f32_16x16x32_bf16(ah[mi], bh, acc[mi][ni], 0, 0, 0);
                acc[mi][ni] = __builtin_amdgcn_mfma_f32_16x16x32_bf16(al[mi], bh, acc[mi][ni], 0, 0, 0);
                acc[mi][ni] = __builtin_amdgcn_mfma_f32_16x16x32_bf16(ah[mi], bl, acc[mi][ni], 0, 0, 0);
            }
        }
        __syncthreads();
    }

    // Epilogue: C/D layout col = lane&15, row = (lane>>4)*4 + reg  [m89]
#pragma unroll
    for (int mi = 0; mi < 4; ++mi)
#pragma unroll
        for (int r = 0; r < 4; ++r) {
            int row = m0 + wm + (mi << 4) + (lq << 2) + r;
            if (row < mClip) {
#pragma unroll
                for (int ni = 0; ni < 4; ++ni) {
                    long long off = (long long)row * ldc + n0 + wn + (ni << 4) + lr;
                    float v = acc[mi][ni][r];
                    if (mode == 2)      atomicAdd(&C[off], v);
                    else                C[off] = v;
                }
            }
        }
}

// Generic batched GEMM. grid: (N/128, mTiles*kChunks, batch).
__global__ __launch_bounds__(256, 2)
void gemm_one(const float* __restrict__ A, const float* __restrict__ B,
              float* __restrict__ C,
              int K, int lda, int ldb, int ldc,
              long long sA, long long sB, long long sC,
              long long aShift, long long aHi, int mClip, int mode, int kChunks)
{
    A += (long long)blockIdx.z * sA;
    B += (long long)blockIdx.z * sB;
    C += (long long)blockIdx.z * sC;
    int mtile = blockIdx.y / kChunks;
    int kc    = blockIdx.y % kChunks;
    gemm_core(A, B, C, K, lda, ldb, ldc, aShift, aHi, mClip, mode,
              mtile, kc, kChunks, blockIdx.x * 128);
}

// Fused QKV projection: grid (N/128, mTiles, 3); z selects W / output.
__global__ __launch_bounds__(256, 2)
void gemm_qkv(const float* __restrict__ A,
              const float* __restrict__ B0, const float* __restrict__ B1,
              const float* __restrict__ B2,
              float* __restrict__ C0, float* __restrict__ C1, float* __restrict__ C2,
              int K, int lda, int ldb, int ldc)
{
    const float* Bs = (blockIdx.z == 0) ? B0 : (blockIdx.z == 1) ? B1 : B2;
    float*       Cs = (blockIdx.z == 0) ? C0 : (blockIdx.z == 1) ? C1 : C2;
    gemm_core(A, Bs, Cs, K, lda, ldb, ldc, 0, 1LL << 62, 1 << 30, 0,
              blockIdx.y, 0, 1, blockIdx.x * 128);
}

// Column softmax (normalize over QUERY axis = rows), scale applied pre-max.
// grid: (T/64, nb); block 256 = 64 cols x 4 row-segments. In-place fp32.
__global__ __launch_bounds__(256)
void col_softmax(float* __restrict__ S, int T, float scale)
{
    const int tid = threadIdx.x;
    const int jl = tid & 63;
    const int seg = tid >> 6;
    const int j = blockIdx.x * 64 + jl;
    float* Sb = S + (long long)blockIdx.y * T * T;
    const int rps = T >> 2;
    const int r0 = seg * rps;

    float m = -3.4e38f, s = 0.f;
    for (int r = 0; r < rps; ++r) {
        float v = Sb[(long long)(r0 + r) * T + j] * scale;
        float mn = fmaxf(m, v);
        s = s * __expf(m - mn) + __expf(v - mn);
        m = mn;
    }
    __shared__ float sm[4][64], ss[4][64];
    sm[seg][jl] = m;
    ss[seg][jl] = s;
    __syncthreads();
    float mt = -3.4e38f, st = 0.f;
#pragma unroll
    for (int q = 0; q < 4; ++q) {
        float mq = sm[q][jl], sq = ss[q][jl];
        float mn = fmaxf(mt, mq);
        st = st * __expf(mt - mn) + sq * __expf(mq - mn);
        mt = mn;
    }
    const float inv = 1.f / st;
    for (int r = 0; r < rps; ++r) {
        long long off = (long long)(r0 + r) * T + j;
        Sb[off] = __expf(Sb[off] * scale - mt) * inv;
    }
}

extern "C" void kernel_launch(void* const* d_in, const int* in_sizes, int n_in,
                              void* d_out, int out_size, void* d_ws, size_t ws_size,
                              hipStream_t stream)
{
    const float* x  = (const float*)d_in[0];   // (B,T,E)
    const float* WQ = (const float*)d_in[1];   // (H,E,E)
    const float* WK = (const float*)d_in[2];
    const float* WV = (const float*)d_in[3];
    const float* WO = (const float*)d_in[4];   // (H*E, E)
    float* out = (float*)d_out;                // (B,T,E)

    const int B = 8, T = 1024, E = 768, H = 12;
    const long long TE = (long long)T * E;     // 786432
    const long long TT = (long long)T * T;     // 1048576
    const long long HE = (long long)H * E;     // 9216
    const long long BIG = 1LL << 62;
    const int NOCLIP = 1 << 30;

    // Chunking: one slice = Q,K,V,Z (TE each) + S (TT) fp32 = 16 MiB.
    // Profile evidence (round 3/4): NC=8 path runs -> ws_size >= 128 MiB.
    const long long sliceF = 4 * TE + TT;
    long long wsF = (long long)(ws_size / 4);
    int NC = (int)(wsF / sliceF);
    if (NC < 1) NC = 1;
    if (NC > B) NC = B;

    float* Qh = (float*)d_ws;
    float* Kh = Qh + (size_t)NC * TE;
    float* Vh = Kh + (size_t)NC * TE;
    float* Zh = Vh + (size_t)NC * TE;
    float* Sh = Zh + (size_t)NC * TE;

    hipMemsetAsync(out, 0, (size_t)B * TE * sizeof(float), stream);

    dim3 blk(256);

    for (int h = 0; h < H; ++h) {
        // Quirky-reshape window: out row i reads Zc flat [i*9216,(i+1)*9216);
        // head h owns flat [h*786432,(h+1)*786432). Bounds multiples of 768.
        const int i_lo = (int)(((long long)h * TE) / HE);
        const long long aShift = (long long)i_lo * HE - (long long)h * TE;

        for (int b0 = 0; b0 < B; b0 += NC) {
            const int nb = (B - b0 < NC) ? (B - b0) : NC;

            // Fused Q/K/V projections: (nb*T x E) @ (E x E), z selects W.
            dim3 gp(E / 128, nb * T / 128, 3);
            gemm_qkv<<<gp, blk, 0, stream>>>(x + (long long)b0 * TE,
                WQ + (size_t)h * E * E, WK + (size_t)h * E * E,
                WV + (size_t)h * E * E, Qh, Kh, Vh, E, E, E, E);

            // Scores: Q_b (T x E) @ K_b flat reinterpreted as (E x T), ldb=T.
            dim3 gs(T / 128, T / 128, nb);
            gemm_one<<<gs, blk, 0, stream>>>(Qh, Kh, Sh, E, E, T, T,
                TE, TE, TT, 0, BIG, NOCLIP, 0, 1);

            // Softmax over query axis with 1/sqrt(T) pre-scale (in place).
            col_softmax<<<dim3(T / 64, nb), blk, 0, stream>>>(Sh, T, 0.03125f);

            // Z = A (T x T) @ V_b (T x E)
            dim3 gz(E / 128, T / 128, nb);
            gemm_one<<<gz, blk, 0, stream>>>(Sh, Vh, Zh, T, T, E, E,
                TT, TE, TE, 0, BIG, NOCLIP, 0, 1);

            // Final projection contribution of head h, K-SPLIT x6 + atomics:
            // out_b[i_lo+m,:] += A_h @ WO, A_h[m,k] = Zflat[m*9216+k+aShift]
            dim3 gf(E / 128, 6, nb);   // y = k-chunks (single m-tile)
            gemm_one<<<gf, blk, 0, stream>>>(Zh, WO,
                out + (long long)b0 * TE + (long long)i_lo * E,
                (int)HE, (int)HE, E, E, TE, 0, TE,
                aShift, TE, T - i_lo, 2, 6);
        }
    }
}